// Round 2
// baseline (36.133 us; speedup 1.0000x reference)
//
#include <hip/hip_runtime.h>

// Fused 2-level 3D Haar DWT (Patcher3D, patch_size=4).
// Input  x  : [4, 3, 33, 256, 256] f32  (frame 0 logically repeated 4x on T)
// Output out: [4, 192, 9, 64, 64]  f32
// out[b, band2*24 + band1*3 + c, t2, h2, w2] =
//   (1/64) * sum_{u,v,w in [0,4)} Wt[u]*Wh[v]*Ww[w] * xin[b,c,4t2+u,4h2+v,4w2+w]
// where per-axis weight rows are the order-4 Hadamard rows indexed by (b2,b1),
// and xin frame = max(4*t2+u-3, 0).

#define HW_IN   65536      // 256*256
#define THW_OUT 36864      // 9*64*64

__global__ __launch_bounds__(256) void patcher3d_haar2(
    const float* __restrict__ x, float* __restrict__ out)
{
    const int lane = threadIdx.x & 63;
    const int wave = threadIdx.x >> 6;

    int gid = blockIdx.x;
    const int h2g = gid & 15;  gid >>= 4;   // 16 groups of 4 h2 rows
    const int t2  = gid % 9;   gid /= 9;
    const int c   = gid % 3;
    const int b   = gid / 3;

    const int h2 = (h2g << 2) | wave;   // [0,64)
    const int w2 = lane;                // [0,64)

    const float* __restrict__ xp = x + (size_t)(b * 3 + c) * 33 * HW_IN;

    float tacc[4][4][4];   // [pt][ph][pw], p = b2*2 + b1
#pragma unroll
    for (int i = 0; i < 4; ++i)
#pragma unroll
        for (int j = 0; j < 4; ++j)
#pragma unroll
            for (int k = 0; k < 4; ++k) tacc[i][j][k] = 0.0f;

#pragma unroll
    for (int u = 0; u < 4; ++u) {
        int tf = 4 * t2 + u - 3;
        tf = tf < 0 ? 0 : tf;   // repeated first frame
        const float* __restrict__ rowp =
            xp + (size_t)tf * HW_IN + (size_t)(h2 * 4) * 256 + (w2 * 4);

        float hacc[4][4];
#pragma unroll
        for (int j = 0; j < 4; ++j)
#pragma unroll
            for (int k = 0; k < 4; ++k) hacc[j][k] = 0.0f;

#pragma unroll
        for (int v = 0; v < 4; ++v) {
            const float4 r = *reinterpret_cast<const float4*>(rowp + v * 256);

            // W-axis 4-point WHT (8 adds)
            const float sA = r.x + r.y, dA = r.x - r.y;
            const float sB = r.z + r.w, dB = r.z - r.w;
            float sw[4];
            sw[0] = sA + sB;   // (L2,L1)
            sw[1] = dA + dB;   // (L2,H1)
            sw[2] = sA - sB;   // (H2,L1)
            sw[3] = dA - dB;   // (H2,H1)

            // H-axis accumulate with compile-time +-1 weights
#pragma unroll
            for (int ph = 0; ph < 4; ++ph) {
                const bool neg = ((((ph >> 1) & (v >> 1)) ^ ((ph & 1) & (v & 1))) != 0);
                if (neg) {
#pragma unroll
                    for (int pw = 0; pw < 4; ++pw) hacc[ph][pw] -= sw[pw];
                } else {
#pragma unroll
                    for (int pw = 0; pw < 4; ++pw) hacc[ph][pw] += sw[pw];
                }
            }
        }

        // T-axis accumulate
#pragma unroll
        for (int pt = 0; pt < 4; ++pt) {
            const bool neg = ((((pt >> 1) & (u >> 1)) ^ ((pt & 1) & (u & 1))) != 0);
            if (neg) {
#pragma unroll
                for (int j = 0; j < 4; ++j)
#pragma unroll
                    for (int k = 0; k < 4; ++k) tacc[pt][j][k] -= hacc[j][k];
            } else {
#pragma unroll
                for (int j = 0; j < 4; ++j)
#pragma unroll
                    for (int k = 0; k < 4; ++k) tacc[pt][j][k] += hacc[j][k];
            }
        }
    }

    // Store: out[b][ch][t2][h2][w2], ch = band2*24 + band1*3 + c
    const float scale = 1.0f / 64.0f;
    float* __restrict__ ob = out + (size_t)b * 192 * THW_OUT
                                 + (size_t)t2 * (64 * 64) + h2 * 64 + w2;
#pragma unroll
    for (int pt = 0; pt < 4; ++pt)
#pragma unroll
        for (int ph = 0; ph < 4; ++ph)
#pragma unroll
            for (int pw = 0; pw < 4; ++pw) {
                const int band2 = ((pt >> 1) << 2) | ((ph >> 1) << 1) | (pw >> 1);
                const int band1 = ((pt & 1) << 2) | ((ph & 1) << 1) | (pw & 1);
                const int ch = band2 * 24 + band1 * 3 + c;
                ob[(size_t)ch * THW_OUT] = tacc[pt][ph][pw] * scale;
            }
}

extern "C" void kernel_launch(void* const* d_in, const int* in_sizes, int n_in,
                              void* d_out, int out_size, void* d_ws, size_t ws_size,
                              hipStream_t stream)
{
    const float* x = (const float*)d_in[0];
    float* out = (float*)d_out;
    // grid: 4 (b) * 3 (c) * 9 (t2) * 16 (h2 groups) = 1728 blocks of 256 threads
    dim3 grid(1728), block(256);
    hipLaunchKernelGGL(patcher3d_haar2, grid, block, 0, stream, x, out);
}